// Round 5
// baseline (534.191 us; speedup 1.0000x reference)
//
#include <hip/hip_runtime.h>
#include <hip/hip_bf16.h>

#define NN    8192
#define NFEAT 512
#define NHID  256
#define NCLASS 16
#define ELLW  256

typedef __hip_bfloat16 bf16;
typedef unsigned short u16;
typedef __bf16 bf16x8 __attribute__((ext_vector_type(8)));
typedef float  f32x4  __attribute__((ext_vector_type(4)));
typedef int    i32x4  __attribute__((ext_vector_type(4)));

__device__ inline float bf2f(u16 u) { return __uint_as_float(((unsigned int)u) << 16); }
__device__ inline u16 f2bfu(float f) {
  bf16 b = __float2bfloat16(f);
  u16 u;
  __builtin_memcpy(&u, &b, 2);
  return u;
}

// ---------------- dtype probe (FALLBACK only, when in_sizes is ambiguous) ----------------
__device__ inline int nanhits(unsigned w) {
  return ((((w >> 7) & 0xFF) == 0xFF) ? 1 : 0) + ((((w >> 23) & 0xFF) == 0xFF) ? 1 : 0);
}

__global__ __launch_bounds__(256) void probe_dtype2(const uint4* __restrict__ a, int nchunks_a,
                                                    const uint4* __restrict__ b, int nchunks_b,
                                                    int* __restrict__ cnt) {
  int c = 0;
  int gid = blockIdx.x * 256 + threadIdx.x;
  int stride = gridDim.x * 256;
  for (int i = gid; i < nchunks_a; i += stride * 4) {
    uint4 v = a[i];
    c += nanhits(v.x) + nanhits(v.y) + nanhits(v.z) + nanhits(v.w);
  }
  for (int i = gid; i < nchunks_b; i += stride) {
    uint4 v = b[i];
    c += nanhits(v.x) + nanhits(v.y) + nanhits(v.z) + nanhits(v.w);
  }
  if (c) atomicAdd(cnt, c);
}

// ---- k1: convert x (vec4) + W1^T only — the two inputs gemm1 needs ----
__global__ __launch_bounds__(256) void convert_xW1(const void* __restrict__ x_raw,
                                                   const void* __restrict__ W1r,
                                                   bf16* __restrict__ xc,
                                                   bf16* __restrict__ W1t,
                                                   const int* __restrict__ flagcnt,
                                                   int mode) {
  bool isf32 = (mode < 0) ? (*flagcnt > 16) : (mode != 0);
  const int n4x = NN * NFEAT / 4;
  const int n1 = NFEAT * NHID;
  const int total = n4x + n1;
  for (int i = blockIdx.x * 256 + threadIdx.x; i < total; i += gridDim.x * 256) {
    if (i < n4x) {
      ushort4 o;
      if (isf32) {
        f32x4 v = ((const f32x4*)x_raw)[i];
        o.x = f2bfu(v.x); o.y = f2bfu(v.y); o.z = f2bfu(v.z); o.w = f2bfu(v.w);
      } else {
        o = ((const ushort4*)x_raw)[i];
      }
      ((ushort4*)xc)[i] = o;
    } else {
      int j = i - n4x;
      int k = j / NHID, n = j % NHID;
      float v = isf32 ? ((const float*)W1r)[j] : __bfloat162float(((const bf16*)W1r)[j]);
      W1t[(size_t)n * NFEAT + k] = __float2bfloat16(v);
    }
  }
}

// ------- shared MFMA GEMM tile body (TM=TN=64, TK=64, register prefetch) -------
// optional fused epilogue: f12[row]   += C_row . avec[0:N]
//                          f12[NN+row]+= C_row . avec[N:2N]   (f12 pre-zeroed)
#define TM 64
#define TN 64
#define LDSP 72

__device__ __forceinline__ void gemm_tile(int bm, int bn,
                                          const bf16* __restrict__ A, int lda,
                                          const bf16* __restrict__ Bt, int ldb,
                                          bf16* __restrict__ C, int ldc, int K,
                                          const float* __restrict__ avec,
                                          float* __restrict__ f12,
                                          bf16* sA, bf16* sB) {
  int t = threadIdx.x;
  int wave = t >> 6, lane = t & 63;
  int quad = lane >> 4, l16 = lane & 15;
  f32x4 acc[4] = {};

  int srow = t >> 2;
  int sk   = (t & 3) * 16;
  const size_t abase = (size_t)(bm * TM + srow) * lda + sk;
  const size_t bbase = (size_t)(bn * TN + srow) * ldb + sk;

  uint4 pa0 = *(const uint4*)&A[abase];
  uint4 pa1 = *(const uint4*)&A[abase + 8];
  uint4 pb0 = *(const uint4*)&Bt[bbase];
  uint4 pb1 = *(const uint4*)&Bt[bbase + 8];

  for (int kt = 0; kt < K; kt += 64) {
    *(uint4*)&sA[srow * LDSP + sk]     = pa0;
    *(uint4*)&sA[srow * LDSP + sk + 8] = pa1;
    *(uint4*)&sB[srow * LDSP + sk]     = pb0;
    *(uint4*)&sB[srow * LDSP + sk + 8] = pb1;
    __syncthreads();
    if (kt + 64 < K) {
      pa0 = *(const uint4*)&A[abase + kt + 64];
      pa1 = *(const uint4*)&A[abase + kt + 72];
      pb0 = *(const uint4*)&Bt[bbase + kt + 64];
      pb1 = *(const uint4*)&Bt[bbase + kt + 72];
    }
    bf16x8 af0 = *(const bf16x8*)&sA[(wave * 16 + l16) * LDSP + quad * 8];
    bf16x8 af1 = *(const bf16x8*)&sA[(wave * 16 + l16) * LDSP + 32 + quad * 8];
#pragma unroll
    for (int c = 0; c < 4; ++c) {
      bf16x8 bf0 = *(const bf16x8*)&sB[(c * 16 + l16) * LDSP + quad * 8];
      bf16x8 bf1 = *(const bf16x8*)&sB[(c * 16 + l16) * LDSP + 32 + quad * 8];
      acc[c] = __builtin_amdgcn_mfma_f32_16x16x32_bf16(af0, bf0, acc[c], 0, 0, 0);
      acc[c] = __builtin_amdgcn_mfma_f32_16x16x32_bf16(af1, bf1, acc[c], 0, 0, 0);
    }
    __syncthreads();
  }
  int row0 = bm * TM + wave * 16 + quad * 4;
  int col0 = bn * TN;
#pragma unroll
  for (int c = 0; c < 4; ++c) {
#pragma unroll
    for (int r = 0; r < 4; ++r) {
      C[(size_t)(row0 + r) * ldc + col0 + c * 16 + l16] = __float2bfloat16(acc[c][r]);
    }
  }
  if (f12) {
    float av1[4], av2[4];
#pragma unroll
    for (int c = 0; c < 4; ++c) {
      int col = col0 + c * 16 + l16;
      av1[c] = avec[col];
      av2[c] = avec[NHID + col];
    }
#pragma unroll
    for (int r = 0; r < 4; ++r) {
      float s1 = 0.f, s2 = 0.f;
#pragma unroll
      for (int c = 0; c < 4; ++c) {
        s1 += acc[c][r] * av1[c];
        s2 += acc[c][r] * av2[c];
      }
      for (int m = 1; m <= 8; m <<= 1) {
        s1 += __shfl_xor(s1, m, 64);
        s2 += __shfl_xor(s2, m, 64);
      }
      if (l16 == 0) {
        atomicAdd(&f12[row0 + r], s1);
        atomicAdd(&f12[NN + row0 + r], s2);
      }
    }
  }
}

__global__ __launch_bounds__(256) void gemm_bt(const bf16* __restrict__ A, int lda,
                                               const bf16* __restrict__ Bt, int ldb,
                                               bf16* __restrict__ C, int ldc, int K,
                                               const float* __restrict__ avec,
                                               float* __restrict__ f12) {
  __shared__ __align__(16) bf16 sAB[2 * TM * LDSP];
  gemm_tile(blockIdx.x, blockIdx.y, A, lda, Bt, ldb, C, ldc, K, avec, f12,
            sAB, sAB + TM * LDSP);
}

// ======== k2: fused  build_ell (blocks 0..NN-1)  ∥  gemm1 (next 512)  ∥  convert_rest+f12zero ========
#define GB1 ((NN / TM) * (NHID / TN))   // 512 gemm1 tiles
#define CVB 64                          // convert_rest blocks

__global__ __launch_bounds__(256) void ell_gemm1(const int* __restrict__ adj,
                                                 int* __restrict__ ell_cnt,
                                                 u16* __restrict__ ell_col,
                                                 const bf16* __restrict__ xc,
                                                 const bf16* __restrict__ W1t,
                                                 bf16* __restrict__ XW,
                                                 const void* __restrict__ War,
                                                 const void* __restrict__ b1r,
                                                 const void* __restrict__ avr,
                                                 const void* __restrict__ W3r,
                                                 const void* __restrict__ b3r,
                                                 bf16* __restrict__ Wat,
                                                 float* __restrict__ b1f,
                                                 float* __restrict__ avecf,
                                                 float* __restrict__ W3f,
                                                 float* __restrict__ b3f,
                                                 float* __restrict__ f12a,
                                                 const int* __restrict__ flagcnt,
                                                 int mode) {
  __shared__ __align__(16) bf16 sAB[2 * TM * LDSP];
  __shared__ int cnt;
  int b = blockIdx.x;
  if (b < NN) {
    // ---- build_ell: one row per block, ballot compaction, nontemporal adj reads ----
    int row = b;
    if (threadIdx.x == 0) cnt = 0;
    __syncthreads();
    const i32x4* arow = (const i32x4*)(adj + (size_t)row * NN);
    u16* crow = ell_col + (size_t)row * ELLW;
    int lane = threadIdx.x & 63;
    unsigned long long lt = ((unsigned long long)1 << lane) - 1;
    for (int j4 = threadIdx.x; j4 < NN / 4; j4 += 256) {
      i32x4 v = __builtin_nontemporal_load(&arow[j4]);
      unsigned long long m0 = __ballot(v.x != 0);
      unsigned long long m1 = __ballot(v.y != 0);
      unsigned long long m2 = __ballot(v.z != 0);
      unsigned long long m3 = __ballot(v.w != 0);
      int c0 = __popcll(m0), c1 = __popcll(m1), c2 = __popcll(m2), c3 = __popcll(m3);
      int total = c0 + c1 + c2 + c3;
      int base = 0;
      if (lane == 0 && total) base = atomicAdd(&cnt, total);
      base = __shfl(base, 0, 64);
      int col = j4 * 4;
      if (v.x) { int p = base + __popcll(m0 & lt);                 if (p < ELLW) crow[p] = (u16)col;       }
      if (v.y) { int p = base + c0 + __popcll(m1 & lt);            if (p < ELLW) crow[p] = (u16)(col + 1); }
      if (v.z) { int p = base + c0 + c1 + __popcll(m2 & lt);       if (p < ELLW) crow[p] = (u16)(col + 2); }
      if (v.w) { int p = base + c0 + c1 + c2 + __popcll(m3 & lt);  if (p < ELLW) crow[p] = (u16)(col + 3); }
    }
    __syncthreads();
    if (threadIdx.x == 0) ell_cnt[row] = cnt < ELLW ? cnt : ELLW;
  } else if (b < NN + GB1) {
    // ---- gemm1: XW = xc @ W1t^T  (independent of adj; overlaps the ell HBM stream) ----
    int cb = b - NN;
    int bm = cb % (NN / TM), bn = cb / (NN / TM);
    gemm_tile(bm, bn, xc, NFEAT, W1t, NFEAT, XW, NHID, NFEAT, nullptr, nullptr,
              sAB, sAB + TM * LDSP);
  } else {
    // ---- convert Wa^T / b1 / avec / W3 / b3 + zero f12 (consumed ≥1 launch later) ----
    int cb = b - NN - GB1;
    bool isf32 = (mode < 0) ? (*flagcnt > 16) : (mode != 0);
    auto rd = [&](const void* p, int i) -> float {
      return isf32 ? ((const float*)p)[i] : __bfloat162float(((const bf16*)p)[i]);
    };
    int gid = cb * 256 + threadIdx.x;
    const int gstride = CVB * 256;
    for (int i = gid; i < 2 * NN; i += gstride) f12a[i] = 0.f;
    const int n2 = NHID * NHID;
    const int n3 = n2 + NHID;
    const int n4 = n3 + 2 * NHID;
    const int n5 = n4 + NHID * NCLASS;
    const int n6 = n5 + NCLASS;
    for (int j = gid; j < n6; j += gstride) {
      if (j < n2)      { int k = j / NHID, n = j % NHID; Wat[(size_t)n * NHID + k] = __float2bfloat16(rd(War, j)); }
      else if (j < n3) b1f[j - n2] = rd(b1r, j - n2);
      else if (j < n4) avecf[j - n3] = rd(avr, j - n3);
      else if (j < n5) W3f[j - n4] = rd(W3r, j - n4);
      else             b3f[j - n5] = rd(b3r, j - n5);
    }
  }
}

// ------- h1: wave per row, 4 cols/lane (full 512B row per wave-load) -------
__global__ __launch_bounds__(256) void spmm_h1(const bf16* __restrict__ XW,
                                               const int* __restrict__ ell_cnt,
                                               const u16* __restrict__ ell_col,
                                               const float* __restrict__ b1,
                                               float* __restrict__ out2,
                                               bf16* __restrict__ h1b) {
  __shared__ int sc[4][ELLW];
  int wave = threadIdx.x >> 6, lane = threadIdx.x & 63;
  int row = blockIdx.x * 4 + wave;
  int nn = ell_cnt[row];
  const u16* cr = ell_col + (size_t)row * ELLW;
  for (int k = lane; k < nn; k += 64) sc[wave][k] = cr[k];
  float a0 = 0.f, a1 = 0.f, a2 = 0.f, a3 = 0.f;
  const int c0 = lane * 4;
#pragma unroll 4
  for (int k = 0; k < nn; ++k) {
    ushort4 v = *(const ushort4*)&XW[(size_t)sc[wave][k] * NHID + c0];
    a0 += bf2f(v.x); a1 += bf2f(v.y); a2 += bf2f(v.z); a3 += bf2f(v.w);
  }
  f32x4 bb = *(const f32x4*)&b1[c0];
  a0 = fmaxf(a0 + bb.x, 0.f);
  a1 = fmaxf(a1 + bb.y, 0.f);
  a2 = fmaxf(a2 + bb.z, 0.f);
  a3 = fmaxf(a3 + bb.w, 0.f);
  f32x4 r; r.x = a0; r.y = a1; r.z = a2; r.w = a3;
  *(f32x4*)&out2[(size_t)row * (NHID + NCLASS) + c0] = r;
  ushort4 h; h.x = f2bfu(a0); h.y = f2bfu(a1); h.z = f2bfu(a2); h.w = f2bfu(a3);
  *(ushort4*)&h1b[(size_t)row * NHID + c0] = h;
}

// ======== PATH A: fused attention — LDS rowbuf, write-early + fused A3 ========
__global__ __launch_bounds__(256) void attn_fused(const bf16* __restrict__ Wh,
                                                  const int* __restrict__ ell_cnt,
                                                  const u16* __restrict__ ell_col,
                                                  const float* __restrict__ f12,
                                                  const float* __restrict__ W3,
                                                  float* __restrict__ att,
                                                  bf16* __restrict__ aout,
                                                  float* __restrict__ A3) {
  __shared__ __align__(16) float rowbuf[NN];       // 32 KB
  __shared__ float p[ELLW];
  __shared__ int scols[ELLW];
  __shared__ float red[8];
  __shared__ __align__(16) float hacc[4][NHID];    // 4 KB
  int row = blockIdx.x, t = threadIdx.x;
  int wave = t >> 6, lane = t & 63;
  int nn = ell_cnt[row];
  const u16* cr = ell_col + (size_t)row * ELLW;
  float f1i = f12[row];
  const float* f2 = f12 + NN;

  f32x4* rb4 = (f32x4*)rowbuf;
  f32x4 z = {0.f, 0.f, 0.f, 0.f};
#pragma unroll
  for (int k = t; k < NN / 4; k += 256) rb4[k] = z;
  for (int k = t; k < nn; k += 256) scols[k] = cr[k];
  __syncthreads();

  float lmax = -1e30f;
  for (int k = t; k < nn; k += 256) {
    float e = f1i + f2[scols[k]];
    e = (e > 0.f) ? e : 0.01f * e;
    p[k] = e;
    lmax = fmaxf(lmax, e);
  }
  for (int o = 32; o > 0; o >>= 1) lmax = fmaxf(lmax, __shfl_down(lmax, o, 64));
  if (lane == 0) red[wave] = lmax;
  __syncthreads();
  float gmax = fmaxf(fmaxf(red[0], red[1]), fmaxf(red[2], red[3]));

  float lsum = 0.f;
  for (int k = t; k < nn; k += 256) {
    float ex = __expf(p[k] - gmax);
    p[k] = ex;
    lsum += ex;
  }
  for (int o = 32; o > 0; o >>= 1) lsum += __shfl_down(lsum, o, 64);
  __syncthreads();                 // all p[] writes visible to all threads
  if (lane == 0) red[4 + wave] = lsum;
  __syncthreads();
  float inv = 1.f / fmaxf(red[4] + red[5] + red[6] + red[7], 1e-30f);

  // scatter normalized probs into LDS rowbuf (zeroed above, barriers since)
  for (int k = t; k < nn; k += 256) rowbuf[scols[k]] = p[k] * inv;
  __syncthreads();                 // rowbuf final

  // WRITE-EARLY: issue the streaming row write now; stores retire while the
  // h_prime gather below executes (disjoint addresses, fire-and-forget)
  f32x4* dst = (f32x4*)(att + (size_t)row * NN);
#pragma unroll
  for (int k = t; k < NN / 4; k += 256) __builtin_nontemporal_store(rb4[k], &dst[k]);

  // h_prime: wave w takes k = w, w+4, ...; each lane owns 4 consecutive cols
  const int c0 = lane * 4;
  float a0 = 0.f, a1 = 0.f, a2 = 0.f, a3 = 0.f;
#pragma unroll 4
  for (int k = wave; k < nn; k += 4) {
    float pk = p[k];
    ushort4 v = *(const ushort4*)&Wh[(size_t)scols[k] * NHID + c0];
    a0 += pk * bf2f(v.x);
    a1 += pk * bf2f(v.y);
    a2 += pk * bf2f(v.z);
    a3 += pk * bf2f(v.w);
  }
  f32x4 pa; pa.x = a0; pa.y = a1; pa.z = a2; pa.w = a3;
  *(f32x4*)&hacc[wave][c0] = pa;
  __syncthreads();   // hacc ready; p/scols re-usable after this point

  // cross-wave reduce + ELU + aout
  float s = (hacc[0][t] + hacc[1][t] + hacc[2][t] + hacc[3][t]) * inv;
  float e = (s > 0.f) ? s : (__expf(s) - 1.f);
  aout[(size_t)row * NHID + t] = __float2bfloat16(e);

  // fused gemm3: A3[row] = elu_row @ W3  (reuse dead p[] / scols[] LDS)
  p[t] = e;
  __syncthreads();
  {
    int cc = t & 15, g = t >> 4, k0 = g * 16;
    float part = 0.f;
#pragma unroll
    for (int j = 0; j < 16; ++j)
      part += p[k0 + j] * W3[(k0 + j) * NCLASS + cc];
    float* parts = (float*)scols;
    parts[t] = part;
    __syncthreads();
    if (t < NCLASS) {
      float s3 = 0.f;
#pragma unroll
      for (int g2 = 0; g2 < 16; ++g2) s3 += parts[g2 * 16 + t];
      A3[(size_t)row * NCLASS + t] = s3;
    }
  }
}

// ======== PATH B fallback kernels ========
__global__ __launch_bounds__(256) void attn_sparse(const bf16* __restrict__ Wh,
                                                   const int* __restrict__ ell_cnt,
                                                   const u16* __restrict__ ell_col,
                                                   const float* __restrict__ f12,
                                                   bf16* __restrict__ aout) {
  __shared__ float p[ELLW];
  __shared__ int scols[ELLW];
  __shared__ float red[8];
  int row = blockIdx.x, t = threadIdx.x;
  int nn = ell_cnt[row];
  const u16* cr = ell_col + (size_t)row * ELLW;
  float f1i = f12[row];
  const float* f2 = f12 + NN;
  for (int k = t; k < nn; k += 256) scols[k] = cr[k];
  __syncthreads();
  float lmax = -1e30f;
  for (int k = t; k < nn; k += 256) {
    float e = f1i + f2[scols[k]];
    e = (e > 0.f) ? e : 0.01f * e;
    p[k] = e;
    lmax = fmaxf(lmax, e);
  }
  for (int o = 32; o > 0; o >>= 1) lmax = fmaxf(lmax, __shfl_down(lmax, o, 64));
  if ((t & 63) == 0) red[t >> 6] = lmax;
  __syncthreads();
  float gmax = fmaxf(fmaxf(red[0], red[1]), fmaxf(red[2], red[3]));
  float lsum = 0.f;
  for (int k = t; k < nn; k += 256) {
    float ex = __expf(p[k] - gmax);
    p[k] = ex;
    lsum += ex;
  }
  for (int o = 32; o > 0; o >>= 1) lsum += __shfl_down(lsum, o, 64);
  __syncthreads();
  if ((t & 63) == 0) red[4 + (t >> 6)] = lsum;
  __syncthreads();
  float inv = 1.f / fmaxf(red[4] + red[5] + red[6] + red[7], 1e-30f);
  float acc = 0.f;
  for (int k = 0; k < nn; ++k)
    acc += p[k] * __bfloat162float(Wh[(size_t)scols[k] * NHID + t]);
  acc *= inv;
  float e = (acc > 0.f) ? acc : (__expf(acc) - 1.f);
  aout[(size_t)row * NHID + t] = __float2bfloat16(e);
}

__global__ __launch_bounds__(256) void attn_dense(const int* __restrict__ adj,
                                                  const float* __restrict__ f12,
                                                  float* __restrict__ att) {
  __shared__ __align__(16) float rowbuf[NN];
  __shared__ float se[ELLW];
  __shared__ int sj[ELLW];
  __shared__ float red[8];
  __shared__ int cnt;
  int row = blockIdx.x, t = threadIdx.x;
  if (t == 0) cnt = 0;
  f32x4* rb4 = (f32x4*)rowbuf;
  f32x4 z = {0.f, 0.f, 0.f, 0.f};
  for (int k = t; k < NN / 4; k += 256) rb4[k] = z;
  float f1i = f12[row];
  const float* f2 = f12 + NN;
  __syncthreads();
  const int4* arow = (const int4*)(adj + (size_t)row * NN);
  for (int j4 = t; j4 < NN / 4; j4 += 256) {
    int4 v = arow[j4];
    int base = j4 * 4;
    if (v.x) { int p = atomicAdd(&cnt, 1); if (p < ELLW) { sj[p] = base;     se[p] = f1i + f2[base];     } }
    if (v.y) { int p = atomicAdd(&cnt, 1); if (p < ELLW) { sj[p] = base + 1; se[p] = f1i + f2[base + 1]; } }
    if (v.z) { int p = atomicAdd(&cnt, 1); if (p < ELLW) { sj[p] = base + 2; se[p] = f1i + f2[base + 2]; } }
    if (v.w) { int p = atomicAdd(&cnt, 1); if (p < ELLW) { sj[p] = base + 3; se[p] = f1i + f2[base + 3]; } }
  }
  __syncthreads();
  int nn = cnt < ELLW ? cnt : ELLW;
  float lmax = -1e30f;
  for (int k = t; k < nn; k += 256) {
    float e = se[k];
    e = (e > 0.f) ? e : 0.01f * e;
    se[k] = e;
    lmax = fmaxf(lmax, e);
  }
  for (int o = 32; o > 0; o >>= 1) lmax = fmaxf(lmax, __shfl_down(lmax, o, 64));
  if ((t & 63) == 0) red[t >> 6] = lmax;
  __syncthreads();
  float gmax = fmaxf(fmaxf(red[0], red[1]), fmaxf(red[2], red[3]));
  float lsum = 0.f;
  for (int k = t; k < nn; k += 256) {
    float ex = __expf(se[k] - gmax);
    se[k] = ex;
    lsum += ex;
  }
  for (int o = 32; o > 0; o >>= 1) lsum += __shfl_down(lsum, o, 64);
  __syncthreads();
  if ((t & 63) == 0) red[4 + (t >> 6)] = lsum;
  __syncthreads();
  float inv = 1.f / fmaxf(red[4] + red[5] + red[6] + red[7], 1e-30f);
  for (int k = t; k < nn; k += 256) rowbuf[sj[k]] = se[k] * inv;
  __syncthreads();
  const f32x4* src = (const f32x4*)rowbuf;
  f32x4* dst = (f32x4*)(att + (size_t)row * NN);
  for (int k = t; k < NN / 4; k += 256) dst[k] = src[k];
}

// ---------------- A3 = a_out @ W3 (f32) — fallback path only ----------------
__global__ __launch_bounds__(256) void gemm3(const bf16* __restrict__ aout,
                                             const float* __restrict__ W3,
                                             float* __restrict__ A3) {
  __shared__ float sW[NHID * NCLASS];
  __shared__ bf16 sa[16 * NHID];
  int t = threadIdx.x;
  for (int k = t; k < NHID * NCLASS; k += 256) sW[k] = W3[k];
  int r0 = blockIdx.x * 16;
  for (int k = t; k < 16 * NHID; k += 256) sa[k] = aout[(size_t)r0 * NHID + k];
  __syncthreads();
  int r = t >> 4, c = t & 15;
  float acc = 0.f;
#pragma unroll 8
  for (int k = 0; k < NHID; ++k)
    acc += __bfloat162float(sa[r * NHID + k]) * sW[k * NCLASS + c];
  A3[(size_t)(r0 + r) * NCLASS + c] = acc;
}

// ------- out2[:,256:272] = spmm(adj, A3) + b3 ; optional sigmoid to out0 -------
__global__ __launch_bounds__(256) void spmm_out2(const float* __restrict__ A3,
                                                 const int* __restrict__ ell_cnt,
                                                 const u16* __restrict__ ell_col,
                                                 const float* __restrict__ b3,
                                                 float* __restrict__ out2,
                                                 float* __restrict__ out0,
                                                 int write_sig) {
  int g = blockIdx.x * 256 + threadIdx.x;
  int row = g >> 4, c = g & 15;
  int nn = ell_cnt[row];
  const u16* cr = ell_col + (size_t)row * ELLW;
  float acc = b3[c];
#pragma unroll 8
  for (int k = 0; k < nn; ++k)
    acc += A3[(size_t)cr[k] * NCLASS + c];
  out2[(size_t)row * (NHID + NCLASS) + NHID + c] = acc;
  if (write_sig) out0[g] = 1.f / (1.f + __expf(-acc));
}

__global__ __launch_bounds__(256) void copy_f32(const float* __restrict__ src,
                                                float* __restrict__ dst, int n) {
  int i = blockIdx.x * 256 + threadIdx.x;
  if (i < n) dst[i] = src[i];
}

__global__ __launch_bounds__(256) void sigmoid_from_out2(const float* __restrict__ out2,
                                                         float* __restrict__ out0) {
  int g = blockIdx.x * 256 + threadIdx.x;
  int row = g >> 4, c = g & 15;
  float v = out2[(size_t)row * (NHID + NCLASS) + NHID + c];
  out0[g] = 1.f / (1.f + __expf(-v));
}

extern "C" void kernel_launch(void* const* d_in, const int* in_sizes, int n_in,
                              void* d_out, int out_size, void* d_ws, size_t ws_size,
                              hipStream_t stream) {
  const void* x_raw    = d_in[0];
  const int*  adj      = (const int*)d_in[1];
  const void* W1_raw   = d_in[2];
  const void* b1_raw   = d_in[3];
  const void* Wa_raw   = d_in[4];
  const void* avec_raw = d_in[5];
  const void* W3_raw   = d_in[6];
  const void* b3_raw   = d_in[7];

  float* out0 = (float*)d_out;                               // [8192,16]
  float* out1 = out0 + (size_t)NN * NCLASS;                  // [8192,8192]
  float* out2 = out1 + (size_t)NN * NN;                      // [8192,272]

  const size_t NEED = 36u << 20;
  bool useWS = (d_ws != nullptr) && (ws_size >= NEED);

  char* a = useWS ? (char*)d_ws : (char*)out1;
  size_t o = 0;
  auto carve = [&](size_t bytes) { char* p = a + o; o += (bytes + 4095) & ~(size_t)4095; return p; };
  int*   flag    = (int*)  carve(4096);
  int*   ell_cnt = (int*)  carve((size_t)NN * 4);
  u16*   ell_col = (u16*)  carve((size_t)NN * ELLW * 2);
  bf16*  xc      = (bf16*) carve((size_t)NN * NFEAT * 2);
  bf16*  W1t     = (bf16*) carve((size_t)NHID * NFEAT * 2);
  bf16*  Wat     = (bf16*) carve((size_t)NHID * NHID * 2);
  float* avecf   = (float*)carve((size_t)2 * NHID * 4);
  float* b1f     = (float*)carve((size_t)NHID * 4);
  float* b3f     = (float*)carve((size_t)NCLASS * 4);
  float* W3f     = (float*)carve((size_t)NHID * NCLASS * 4);
  bf16*  XW      = (bf16*) carve((size_t)NN * NHID * 2);
  bf16*  h1b     = (bf16*) carve((size_t)NN * NHID * 2);
  bf16*  Wh      = (bf16*) carve((size_t)NN * NHID * 2);
  float* f12a    = (float*)carve((size_t)2 * NN * 4);
  bf16*  aout    = (bf16*) carve((size_t)NN * NHID * 2);
  float* A3ws    = (float*)carve((size_t)NN * NCLASS * 4);

  float* A3 = useWS ? A3ws : out0;
  float* f12stash = out0;

  // host-side dtype inference from byte sizes; fall back to device probe if ambiguous
  int mode;
  {
    long long sx = in_sizes ? (long long)in_sizes[0] : -1;
    long long sw = in_sizes ? (long long)in_sizes[2] : -1;
    int mx = (sx == (long long)NN * NFEAT * 4) ? 1 : (sx == (long long)NN * NFEAT * 2 ? 0 : -1);
    int mw = (sw == (long long)NFEAT * NHID * 4) ? 1 : (sw == (long long)NFEAT * NHID * 2 ? 0 : -1);
    mode = (mx >= 0 && mx == mw) ? mx : -1;
  }
  if (mode < 0) {
    (void)hipMemsetAsync(flag, 0, 4, stream);
    probe_dtype2<<<256, 256, 0, stream>>>((const uint4*)x_raw, NN * NFEAT / 8,
                                          (const uint4*)W1_raw, NFEAT * NHID / 8, flag);
  }

  convert_xW1<<<2048, 256, 0, stream>>>(x_raw, W1_raw, xc, W1t, flag, mode);
  ell_gemm1<<<NN + GB1 + CVB, 256, 0, stream>>>(adj, ell_cnt, ell_col,
                                                xc, W1t, XW,
                                                Wa_raw, b1_raw, avec_raw, W3_raw, b3_raw,
                                                Wat, b1f, avecf, W3f, b3f,
                                                f12a, flag, mode);
  spmm_h1<<<NN / 4, 256, 0, stream>>>(XW, ell_cnt, ell_col, b1f, out2, h1b);
  gemm_bt<<<dim3(NN / TM, NHID / TN), 256, 0, stream>>>(h1b, NHID, Wat, NHID, Wh, NHID, NHID,
                                                        avecf, f12a);

  if (useWS) {
    attn_fused<<<NN, 256, 0, stream>>>(Wh, ell_cnt, ell_col, f12a, W3f, out1, aout, A3);
    spmm_out2<<<NN * NCLASS / 256, 256, 0, stream>>>(A3, ell_cnt, ell_col, b3f, out2, out0, 1);
  } else {
    attn_sparse<<<NN, 256, 0, stream>>>(Wh, ell_cnt, ell_col, f12a, aout);
    gemm3<<<NN / 16, 256, 0, stream>>>(aout, W3f, A3);
    spmm_out2<<<NN * NCLASS / 256, 256, 0, stream>>>(A3, ell_cnt, ell_col, b3f, out2, out0, 0);
    copy_f32<<<(2 * NN + 255) / 256, 256, 0, stream>>>(f12a, f12stash, 2 * NN);
    attn_dense<<<NN, 256, 0, stream>>>(adj, f12stash, out1);
    sigmoid_from_out2<<<NN * NCLASS / 256, 256, 0, stream>>>(out2, out0);
  }
}

// Round 6
// 522.120 us; speedup vs baseline: 1.0231x; 1.0231x over previous
//
#include <hip/hip_runtime.h>
#include <hip/hip_bf16.h>

#define NN    8192
#define NFEAT 512
#define NHID  256
#define NCLASS 16
#define ELLW  256
#define CONVB 2048   // convert blocks appended after the NN build_ell blocks

typedef __hip_bfloat16 bf16;
typedef unsigned short u16;
typedef __bf16 bf16x8 __attribute__((ext_vector_type(8)));
typedef float  f32x4  __attribute__((ext_vector_type(4)));
typedef int    i32x4  __attribute__((ext_vector_type(4)));

__device__ inline float bf2f(u16 u) { return __uint_as_float(((unsigned int)u) << 16); }
__device__ inline u16 f2bfu(float f) {
  bf16 b = __float2bfloat16(f);
  u16 u;
  __builtin_memcpy(&u, &b, 2);
  return u;
}

// ---------------- dtype probe (FALLBACK only, when in_sizes is ambiguous) ----------------
__device__ inline int nanhits(unsigned w) {
  return ((((w >> 7) & 0xFF) == 0xFF) ? 1 : 0) + ((((w >> 23) & 0xFF) == 0xFF) ? 1 : 0);
}

__global__ __launch_bounds__(256) void probe_dtype2(const uint4* __restrict__ a, int nchunks_a,
                                                    const uint4* __restrict__ b, int nchunks_b,
                                                    int* __restrict__ cnt) {
  int c = 0;
  int gid = blockIdx.x * 256 + threadIdx.x;
  int stride = gridDim.x * 256;
  for (int i = gid; i < nchunks_a; i += stride * 4) {
    uint4 v = a[i];
    c += nanhits(v.x) + nanhits(v.y) + nanhits(v.z) + nanhits(v.w);
  }
  for (int i = gid; i < nchunks_b; i += stride) {
    uint4 v = b[i];
    c += nanhits(v.x) + nanhits(v.y) + nanhits(v.z) + nanhits(v.w);
  }
  if (c) atomicAdd(cnt, c);
}

// ======== fused prep: build_ell (blocks 0..NN-1) + convert/f12-zero (blocks NN..NN+CONVB-1) ========
// mode: 1 = f32 inputs, 0 = bf16 inputs, -1 = read device flag (fallback probe ran)
__global__ __launch_bounds__(256) void prep_all(const int* __restrict__ adj,
                                                int* __restrict__ ell_cnt,
                                                u16* __restrict__ ell_col,
                                                const void* __restrict__ x_raw,
                                                const void* __restrict__ W1r,
                                                const void* __restrict__ War,
                                                const void* __restrict__ b1r,
                                                const void* __restrict__ avr,
                                                const void* __restrict__ W3r,
                                                const void* __restrict__ b3r,
                                                bf16* __restrict__ xc,
                                                bf16* __restrict__ W1t,
                                                bf16* __restrict__ Wat,
                                                float* __restrict__ b1f,
                                                float* __restrict__ avecf,
                                                float* __restrict__ W3f,
                                                float* __restrict__ b3f,
                                                float* __restrict__ f12a,
                                                const int* __restrict__ flagcnt,
                                                int mode) {
  __shared__ int cnt;
  int b = blockIdx.x;
  if (b < NN) {
    // ---- build_ell: one row per block, ballot compaction, nontemporal adj reads ----
    int row = b;
    if (threadIdx.x == 0) cnt = 0;
    __syncthreads();
    const i32x4* arow = (const i32x4*)(adj + (size_t)row * NN);
    u16* crow = ell_col + (size_t)row * ELLW;
    int lane = threadIdx.x & 63;
    unsigned long long lt = ((unsigned long long)1 << lane) - 1;
    for (int j4 = threadIdx.x; j4 < NN / 4; j4 += 256) {
      i32x4 v = __builtin_nontemporal_load(&arow[j4]);
      unsigned long long m0 = __ballot(v.x != 0);
      unsigned long long m1 = __ballot(v.y != 0);
      unsigned long long m2 = __ballot(v.z != 0);
      unsigned long long m3 = __ballot(v.w != 0);
      int c0 = __popcll(m0), c1 = __popcll(m1), c2 = __popcll(m2), c3 = __popcll(m3);
      int total = c0 + c1 + c2 + c3;
      int base = 0;
      if (lane == 0 && total) base = atomicAdd(&cnt, total);
      base = __shfl(base, 0, 64);
      int col = j4 * 4;
      if (v.x) { int p = base + __popcll(m0 & lt);                 if (p < ELLW) crow[p] = (u16)col;       }
      if (v.y) { int p = base + c0 + __popcll(m1 & lt);            if (p < ELLW) crow[p] = (u16)(col + 1); }
      if (v.z) { int p = base + c0 + c1 + __popcll(m2 & lt);       if (p < ELLW) crow[p] = (u16)(col + 2); }
      if (v.w) { int p = base + c0 + c1 + c2 + __popcll(m3 & lt);  if (p < ELLW) crow[p] = (u16)(col + 3); }
    }
    __syncthreads();
    if (threadIdx.x == 0) ell_cnt[row] = cnt < ELLW ? cnt : ELLW;
  } else {
    // ---- convert + f12 zero: grid-stride over CONVB blocks ----
    int cb = b - NN;
    bool isf32 = (mode < 0) ? (*flagcnt > 16) : (mode != 0);
    auto rd = [&](const void* p, int i) -> float {
      return isf32 ? ((const float*)p)[i] : __bfloat162float(((const bf16*)p)[i]);
    };
    int gid = cb * 256 + threadIdx.x;
    const int gstride = CONVB * 256;
    for (int i = gid; i < 2 * NN; i += gstride) f12a[i] = 0.f;
    const int n4x = NN * NFEAT / 4;          // x handled 4-wide
    const int n1 = NFEAT * NHID;
    const int n2 = n1 + NHID * NHID;
    const int n3 = n2 + NHID;
    const int n4 = n3 + 2 * NHID;
    const int n5 = n4 + NHID * NCLASS;
    const int n6 = n5 + NCLASS;
    const int total = n4x + n6;
    for (int i = gid; i < total; i += gstride) {
      if (i < n4x) {
        ushort4 o;
        if (isf32) {
          f32x4 v = ((const f32x4*)x_raw)[i];
          o.x = f2bfu(v.x); o.y = f2bfu(v.y); o.z = f2bfu(v.z); o.w = f2bfu(v.w);
        } else {
          o = ((const ushort4*)x_raw)[i];
        }
        ((ushort4*)xc)[i] = o;
      } else {
        int j = i - n4x;
        if (j < n1)      { int k = j / NHID, n = j % NHID; W1t[(size_t)n * NFEAT + k] = __float2bfloat16(rd(W1r, j)); }
        else if (j < n2) { int q = j - n1; int k = q / NHID, n = q % NHID; Wat[(size_t)n * NHID + k] = __float2bfloat16(rd(War, q)); }
        else if (j < n3) b1f[j - n2] = rd(b1r, j - n2);
        else if (j < n4) avecf[j - n3] = rd(avr, j - n3);
        else if (j < n5) W3f[j - n4] = rd(W3r, j - n4);
        else             b3f[j - n5] = rd(b3r, j - n5);
      }
    }
  }
}

// ------- bf16 MFMA GEMM, TK=64, register prefetch across barrier -------
// optional fused epilogue: f12[row]   += C_row . avec[0:N]
//                          f12[NN+row]+= C_row . avec[N:2N]   (f12 pre-zeroed)
#define TM 64
#define TN 64
#define LDSP 72

__global__ __launch_bounds__(256) void gemm_bt(const bf16* __restrict__ A, int lda,
                                               const bf16* __restrict__ Bt, int ldb,
                                               bf16* __restrict__ C, int ldc, int K,
                                               const float* __restrict__ avec,
                                               float* __restrict__ f12) {
  __shared__ __align__(16) bf16 sA[TM * LDSP];
  __shared__ __align__(16) bf16 sB[TN * LDSP];
  int bm = blockIdx.x, bn = blockIdx.y;
  int t = threadIdx.x;
  int wave = t >> 6, lane = t & 63;
  int quad = lane >> 4, l16 = lane & 15;
  f32x4 acc[4] = {};

  int srow = t >> 2;
  int sk   = (t & 3) * 16;
  const size_t abase = (size_t)(bm * TM + srow) * lda + sk;
  const size_t bbase = (size_t)(bn * TN + srow) * ldb + sk;

  uint4 pa0 = *(const uint4*)&A[abase];
  uint4 pa1 = *(const uint4*)&A[abase + 8];
  uint4 pb0 = *(const uint4*)&Bt[bbase];
  uint4 pb1 = *(const uint4*)&Bt[bbase + 8];

  for (int kt = 0; kt < K; kt += 64) {
    *(uint4*)&sA[srow * LDSP + sk]     = pa0;
    *(uint4*)&sA[srow * LDSP + sk + 8] = pa1;
    *(uint4*)&sB[srow * LDSP + sk]     = pb0;
    *(uint4*)&sB[srow * LDSP + sk + 8] = pb1;
    __syncthreads();
    if (kt + 64 < K) {
      pa0 = *(const uint4*)&A[abase + kt + 64];
      pa1 = *(const uint4*)&A[abase + kt + 72];
      pb0 = *(const uint4*)&Bt[bbase + kt + 64];
      pb1 = *(const uint4*)&Bt[bbase + kt + 72];
    }
    bf16x8 af0 = *(const bf16x8*)&sA[(wave * 16 + l16) * LDSP + quad * 8];
    bf16x8 af1 = *(const bf16x8*)&sA[(wave * 16 + l16) * LDSP + 32 + quad * 8];
#pragma unroll
    for (int c = 0; c < 4; ++c) {
      bf16x8 bf0 = *(const bf16x8*)&sB[(c * 16 + l16) * LDSP + quad * 8];
      bf16x8 bf1 = *(const bf16x8*)&sB[(c * 16 + l16) * LDSP + 32 + quad * 8];
      acc[c] = __builtin_amdgcn_mfma_f32_16x16x32_bf16(af0, bf0, acc[c], 0, 0, 0);
      acc[c] = __builtin_amdgcn_mfma_f32_16x16x32_bf16(af1, bf1, acc[c], 0, 0, 0);
    }
    __syncthreads();
  }
  int row0 = bm * TM + wave * 16 + quad * 4;
  int col0 = bn * TN;
#pragma unroll
  for (int c = 0; c < 4; ++c) {
#pragma unroll
    for (int r = 0; r < 4; ++r) {
      C[(size_t)(row0 + r) * ldc + col0 + c * 16 + l16] = __float2bfloat16(acc[c][r]);
    }
  }
  if (f12) {
    float av1[4], av2[4];
#pragma unroll
    for (int c = 0; c < 4; ++c) {
      int col = col0 + c * 16 + l16;
      av1[c] = avec[col];
      av2[c] = avec[NHID + col];
    }
#pragma unroll
    for (int r = 0; r < 4; ++r) {
      float s1 = 0.f, s2 = 0.f;
#pragma unroll
      for (int c = 0; c < 4; ++c) {
        s1 += acc[c][r] * av1[c];
        s2 += acc[c][r] * av2[c];
      }
      // reduce across the 16 lanes (l16) of this quad
      for (int m = 1; m <= 8; m <<= 1) {
        s1 += __shfl_xor(s1, m, 64);
        s2 += __shfl_xor(s2, m, 64);
      }
      if (l16 == 0) {
        atomicAdd(&f12[row0 + r], s1);
        atomicAdd(&f12[NN + row0 + r], s2);
      }
    }
  }
}

// ------- h1: wave per row, 4 cols/lane (full 512B row per wave-load) -------
__global__ __launch_bounds__(256) void spmm_h1(const bf16* __restrict__ XW,
                                               const int* __restrict__ ell_cnt,
                                               const u16* __restrict__ ell_col,
                                               const float* __restrict__ b1,
                                               float* __restrict__ out2,
                                               bf16* __restrict__ h1b) {
  __shared__ int sc[4][ELLW];
  int wave = threadIdx.x >> 6, lane = threadIdx.x & 63;
  int row = blockIdx.x * 4 + wave;
  int nn = ell_cnt[row];
  const u16* cr = ell_col + (size_t)row * ELLW;
  for (int k = lane; k < nn; k += 64) sc[wave][k] = cr[k];
  // per-wave LDS region; compiler-inserted lgkmcnt orders write->read within the wave
  float a0 = 0.f, a1 = 0.f, a2 = 0.f, a3 = 0.f;
  const int c0 = lane * 4;
#pragma unroll 4
  for (int k = 0; k < nn; ++k) {
    ushort4 v = *(const ushort4*)&XW[(size_t)sc[wave][k] * NHID + c0];
    a0 += bf2f(v.x); a1 += bf2f(v.y); a2 += bf2f(v.z); a3 += bf2f(v.w);
  }
  f32x4 bb = *(const f32x4*)&b1[c0];
  a0 = fmaxf(a0 + bb.x, 0.f);
  a1 = fmaxf(a1 + bb.y, 0.f);
  a2 = fmaxf(a2 + bb.z, 0.f);
  a3 = fmaxf(a3 + bb.w, 0.f);
  f32x4 r; r.x = a0; r.y = a1; r.z = a2; r.w = a3;
  *(f32x4*)&out2[(size_t)row * (NHID + NCLASS) + c0] = r;
  ushort4 h; h.x = f2bfu(a0); h.y = f2bfu(a1); h.z = f2bfu(a2); h.w = f2bfu(a3);
  *(ushort4*)&h1b[(size_t)row * NHID + c0] = h;
}

// ======== PATH A: fused attention — LDS rowbuf + fused A3 (= elu @ W3) ========
__global__ __launch_bounds__(256) void attn_fused(const bf16* __restrict__ Wh,
                                                  const int* __restrict__ ell_cnt,
                                                  const u16* __restrict__ ell_col,
                                                  const float* __restrict__ f12,
                                                  const float* __restrict__ W3,
                                                  float* __restrict__ att,
                                                  bf16* __restrict__ aout,
                                                  float* __restrict__ A3) {
  __shared__ __align__(16) float rowbuf[NN];       // 32 KB
  __shared__ float p[ELLW];
  __shared__ int scols[ELLW];
  __shared__ float red[8];
  __shared__ __align__(16) float hacc[4][NHID];    // 4 KB
  int row = blockIdx.x, t = threadIdx.x;
  int wave = t >> 6, lane = t & 63;
  int nn = ell_cnt[row];
  const u16* cr = ell_col + (size_t)row * ELLW;
  float f1i = f12[row];
  const float* f2 = f12 + NN;

  f32x4* rb4 = (f32x4*)rowbuf;
  f32x4 z = {0.f, 0.f, 0.f, 0.f};
#pragma unroll
  for (int k = t; k < NN / 4; k += 256) rb4[k] = z;
  for (int k = t; k < nn; k += 256) scols[k] = cr[k];
  __syncthreads();

  float lmax = -1e30f;
  for (int k = t; k < nn; k += 256) {
    float e = f1i + f2[scols[k]];
    e = (e > 0.f) ? e : 0.01f * e;
    p[k] = e;
    lmax = fmaxf(lmax, e);
  }
  for (int o = 32; o > 0; o >>= 1) lmax = fmaxf(lmax, __shfl_down(lmax, o, 64));
  if (lane == 0) red[wave] = lmax;
  __syncthreads();
  float gmax = fmaxf(fmaxf(red[0], red[1]), fmaxf(red[2], red[3]));

  float lsum = 0.f;
  for (int k = t; k < nn; k += 256) {
    float ex = __expf(p[k] - gmax);
    p[k] = ex;
    lsum += ex;
  }
  for (int o = 32; o > 0; o >>= 1) lsum += __shfl_down(lsum, o, 64);
  __syncthreads();                 // all p[] writes visible to all threads
  if (lane == 0) red[4 + wave] = lsum;
  __syncthreads();
  float inv = 1.f / fmaxf(red[4] + red[5] + red[6] + red[7], 1e-30f);

  // scatter normalized probs into LDS rowbuf (zeroed above, barriers since)
  for (int k = t; k < nn; k += 256) rowbuf[scols[k]] = p[k] * inv;

  // h_prime: wave w takes k = w, w+4, ...; each lane owns 4 consecutive cols
  const int c0 = lane * 4;
  float a0 = 0.f, a1 = 0.f, a2 = 0.f, a3 = 0.f;
#pragma unroll 4
  for (int k = wave; k < nn; k += 4) {
    float pk = p[k];
    ushort4 v = *(const ushort4*)&Wh[(size_t)scols[k] * NHID + c0];
    a0 += pk * bf2f(v.x);
    a1 += pk * bf2f(v.y);
    a2 += pk * bf2f(v.z);
    a3 += pk * bf2f(v.w);
  }
  f32x4 pa; pa.x = a0; pa.y = a1; pa.z = a2; pa.w = a3;
  *(f32x4*)&hacc[wave][c0] = pa;
  __syncthreads();   // gathers done: p/scols now dead, rowbuf final, hacc ready

  // single streaming (nontemporal) write of the full attention row
  f32x4* dst = (f32x4*)(att + (size_t)row * NN);
#pragma unroll
  for (int k = t; k < NN / 4; k += 256) __builtin_nontemporal_store(rb4[k], &dst[k]);

  // cross-wave reduce + ELU + aout
  float s = (hacc[0][t] + hacc[1][t] + hacc[2][t] + hacc[3][t]) * inv;
  float e = (s > 0.f) ? s : (__expf(s) - 1.f);
  aout[(size_t)row * NHID + t] = __float2bfloat16(e);

  // fused gemm3: A3[row] = elu_row @ W3  (reuse dead p[] / scols[] LDS)
  p[t] = e;
  __syncthreads();
  {
    int cc = t & 15, g = t >> 4, k0 = g * 16;
    float part = 0.f;
#pragma unroll
    for (int j = 0; j < 16; ++j)
      part += p[k0 + j] * W3[(k0 + j) * NCLASS + cc];
    float* parts = (float*)scols;
    parts[t] = part;
    __syncthreads();
    if (t < NCLASS) {
      float s3 = 0.f;
#pragma unroll
      for (int g2 = 0; g2 < 16; ++g2) s3 += parts[g2 * 16 + t];
      A3[(size_t)row * NCLASS + t] = s3;
    }
  }
}

// ======== PATH B fallback kernels ========
__global__ __launch_bounds__(256) void attn_sparse(const bf16* __restrict__ Wh,
                                                   const int* __restrict__ ell_cnt,
                                                   const u16* __restrict__ ell_col,
                                                   const float* __restrict__ f12,
                                                   bf16* __restrict__ aout) {
  __shared__ float p[ELLW];
  __shared__ int scols[ELLW];
  __shared__ float red[8];
  int row = blockIdx.x, t = threadIdx.x;
  int nn = ell_cnt[row];
  const u16* cr = ell_col + (size_t)row * ELLW;
  float f1i = f12[row];
  const float* f2 = f12 + NN;
  for (int k = t; k < nn; k += 256) scols[k] = cr[k];
  __syncthreads();
  float lmax = -1e30f;
  for (int k = t; k < nn; k += 256) {
    float e = f1i + f2[scols[k]];
    e = (e > 0.f) ? e : 0.01f * e;
    p[k] = e;
    lmax = fmaxf(lmax, e);
  }
  for (int o = 32; o > 0; o >>= 1) lmax = fmaxf(lmax, __shfl_down(lmax, o, 64));
  if ((t & 63) == 0) red[t >> 6] = lmax;
  __syncthreads();
  float gmax = fmaxf(fmaxf(red[0], red[1]), fmaxf(red[2], red[3]));
  float lsum = 0.f;
  for (int k = t; k < nn; k += 256) {
    float ex = __expf(p[k] - gmax);
    p[k] = ex;
    lsum += ex;
  }
  for (int o = 32; o > 0; o >>= 1) lsum += __shfl_down(lsum, o, 64);
  __syncthreads();
  if ((t & 63) == 0) red[4 + (t >> 6)] = lsum;
  __syncthreads();
  float inv = 1.f / fmaxf(red[4] + red[5] + red[6] + red[7], 1e-30f);
  float acc = 0.f;
  for (int k = 0; k < nn; ++k)
    acc += p[k] * __bfloat162float(Wh[(size_t)scols[k] * NHID + t]);
  acc *= inv;
  float e = (acc > 0.f) ? acc : (__expf(acc) - 1.f);
  aout[(size_t)row * NHID + t] = __float2bfloat16(e);
}

__global__ __launch_bounds__(256) void attn_dense(const int* __restrict__ adj,
                                                  const float* __restrict__ f12,
                                                  float* __restrict__ att) {
  __shared__ __align__(16) float rowbuf[NN];
  __shared__ float se[ELLW];
  __shared__ int sj[ELLW];
  __shared__ float red[8];
  __shared__ int cnt;
  int row = blockIdx.x, t = threadIdx.x;
  if (t == 0) cnt = 0;
  f32x4* rb4 = (f32x4*)rowbuf;
  f32x4 z = {0.f, 0.f, 0.f, 0.f};
  for (int k = t; k < NN / 4; k += 256) rb4[k] = z;
  float f1i = f12[row];
  const float* f2 = f12 + NN;
  __syncthreads();
  const int4* arow = (const int4*)(adj + (size_t)row * NN);
  for (int j4 = t; j4 < NN / 4; j4 += 256) {
    int4 v = arow[j4];
    int base = j4 * 4;
    if (v.x) { int p = atomicAdd(&cnt, 1); if (p < ELLW) { sj[p] = base;     se[p] = f1i + f2[base];     } }
    if (v.y) { int p = atomicAdd(&cnt, 1); if (p < ELLW) { sj[p] = base + 1; se[p] = f1i + f2[base + 1]; } }
    if (v.z) { int p = atomicAdd(&cnt, 1); if (p < ELLW) { sj[p] = base + 2; se[p] = f1i + f2[base + 2]; } }
    if (v.w) { int p = atomicAdd(&cnt, 1); if (p < ELLW) { sj[p] = base + 3; se[p] = f1i + f2[base + 3]; } }
  }
  __syncthreads();
  int nn = cnt < ELLW ? cnt : ELLW;
  float lmax = -1e30f;
  for (int k = t; k < nn; k += 256) {
    float e = se[k];
    e = (e > 0.f) ? e : 0.01f * e;
    se[k] = e;
    lmax = fmaxf(lmax, e);
  }
  for (int o = 32; o > 0; o >>= 1) lmax = fmaxf(lmax, __shfl_down(lmax, o, 64));
  if ((t & 63) == 0) red[t >> 6] = lmax;
  __syncthreads();
  float gmax = fmaxf(fmaxf(red[0], red[1]), fmaxf(red[2], red[3]));
  float lsum = 0.f;
  for (int k = t; k < nn; k += 256) {
    float ex = __expf(se[k] - gmax);
    se[k] = ex;
    lsum += ex;
  }
  for (int o = 32; o > 0; o >>= 1) lsum += __shfl_down(lsum, o, 64);
  __syncthreads();
  if ((t & 63) == 0) red[4 + (t >> 6)] = lsum;
  __syncthreads();
  float inv = 1.f / fmaxf(red[4] + red[5] + red[6] + red[7], 1e-30f);
  for (int k = t; k < nn; k += 256) rowbuf[sj[k]] = se[k] * inv;
  __syncthreads();
  const f32x4* src = (const f32x4*)rowbuf;
  f32x4* dst = (f32x4*)(att + (size_t)row * NN);
  for (int k = t; k < NN / 4; k += 256) dst[k] = src[k];
}

// ---------------- A3 = a_out @ W3 (f32) — fallback path only ----------------
__global__ __launch_bounds__(256) void gemm3(const bf16* __restrict__ aout,
                                             const float* __restrict__ W3,
                                             float* __restrict__ A3) {
  __shared__ float sW[NHID * NCLASS];
  __shared__ bf16 sa[16 * NHID];
  int t = threadIdx.x;
  for (int k = t; k < NHID * NCLASS; k += 256) sW[k] = W3[k];
  int r0 = blockIdx.x * 16;
  for (int k = t; k < 16 * NHID; k += 256) sa[k] = aout[(size_t)r0 * NHID + k];
  __syncthreads();
  int r = t >> 4, c = t & 15;
  float acc = 0.f;
#pragma unroll 8
  for (int k = 0; k < NHID; ++k)
    acc += __bfloat162float(sa[r * NHID + k]) * sW[k * NCLASS + c];
  A3[(size_t)(r0 + r) * NCLASS + c] = acc;
}

// ------- out2[:,256:272] = spmm(adj, A3) + b3 ; optional sigmoid to out0 -------
__global__ __launch_bounds__(256) void spmm_out2(const float* __restrict__ A3,
                                                 const int* __restrict__ ell_cnt,
                                                 const u16* __restrict__ ell_col,
                                                 const float* __restrict__ b3,
                                                 float* __restrict__ out2,
                                                 float* __restrict__ out0,
                                                 int write_sig) {
  int g = blockIdx.x * 256 + threadIdx.x;
  int row = g >> 4, c = g & 15;
  int nn = ell_cnt[row];
  const u16* cr = ell_col + (size_t)row * ELLW;
  float acc = b3[c];
#pragma unroll 8
  for (int k = 0; k < nn; ++k)
    acc += A3[(size_t)cr[k] * NCLASS + c];
  out2[(size_t)row * (NHID + NCLASS) + NHID + c] = acc;
  if (write_sig) out0[g] = 1.f / (1.f + __expf(-acc));
}

__global__ __launch_bounds__(256) void copy_f32(const float* __restrict__ src,
                                                float* __restrict__ dst, int n) {
  int i = blockIdx.x * 256 + threadIdx.x;
  if (i < n) dst[i] = src[i];
}

__global__ __launch_bounds__(256) void sigmoid_from_out2(const float* __restrict__ out2,
                                                         float* __restrict__ out0) {
  int g = blockIdx.x * 256 + threadIdx.x;
  int row = g >> 4, c = g & 15;
  float v = out2[(size_t)row * (NHID + NCLASS) + NHID + c];
  out0[g] = 1.f / (1.f + __expf(-v));
}

extern "C" void kernel_launch(void* const* d_in, const int* in_sizes, int n_in,
                              void* d_out, int out_size, void* d_ws, size_t ws_size,
                              hipStream_t stream) {
  const void* x_raw    = d_in[0];
  const int*  adj      = (const int*)d_in[1];
  const void* W1_raw   = d_in[2];
  const void* b1_raw   = d_in[3];
  const void* Wa_raw   = d_in[4];
  const void* avec_raw = d_in[5];
  const void* W3_raw   = d_in[6];
  const void* b3_raw   = d_in[7];

  float* out0 = (float*)d_out;                               // [8192,16]
  float* out1 = out0 + (size_t)NN * NCLASS;                  // [8192,8192]
  float* out2 = out1 + (size_t)NN * NN;                      // [8192,272]

  const size_t NEED = 36u << 20;
  bool useWS = (d_ws != nullptr) && (ws_size >= NEED);

  char* a = useWS ? (char*)d_ws : (char*)out1;
  size_t o = 0;
  auto carve = [&](size_t bytes) { char* p = a + o; o += (bytes + 4095) & ~(size_t)4095; return p; };
  int*   flag    = (int*)  carve(4096);
  int*   ell_cnt = (int*)  carve((size_t)NN * 4);
  u16*   ell_col = (u16*)  carve((size_t)NN * ELLW * 2);
  bf16*  xc      = (bf16*) carve((size_t)NN * NFEAT * 2);
  bf16*  W1t     = (bf16*) carve((size_t)NHID * NFEAT * 2);
  bf16*  Wat     = (bf16*) carve((size_t)NHID * NHID * 2);
  float* avecf   = (float*)carve((size_t)2 * NHID * 4);
  float* b1f     = (float*)carve((size_t)NHID * 4);
  float* b3f     = (float*)carve((size_t)NCLASS * 4);
  float* W3f     = (float*)carve((size_t)NHID * NCLASS * 4);
  bf16*  XW      = (bf16*) carve((size_t)NN * NHID * 2);
  bf16*  h1b     = (bf16*) carve((size_t)NN * NHID * 2);
  bf16*  Wh      = (bf16*) carve((size_t)NN * NHID * 2);
  float* f12a    = (float*)carve((size_t)2 * NN * 4);
  bf16*  aout    = (bf16*) carve((size_t)NN * NHID * 2);
  float* A3ws    = (float*)carve((size_t)NN * NCLASS * 4);

  float* A3 = useWS ? A3ws : out0;
  float* f12stash = out0;

  // host-side dtype inference from byte sizes; fall back to device probe if ambiguous
  int mode;
  {
    long long sx = in_sizes ? (long long)in_sizes[0] : -1;
    long long sw = in_sizes ? (long long)in_sizes[2] : -1;
    int mx = (sx == (long long)NN * NFEAT * 4) ? 1 : (sx == (long long)NN * NFEAT * 2 ? 0 : -1);
    int mw = (sw == (long long)NFEAT * NHID * 4) ? 1 : (sw == (long long)NFEAT * NHID * 2 ? 0 : -1);
    mode = (mx >= 0 && mx == mw) ? mx : -1;
  }
  if (mode < 0) {
    (void)hipMemsetAsync(flag, 0, 4, stream);
    probe_dtype2<<<256, 256, 0, stream>>>((const uint4*)x_raw, NN * NFEAT / 8,
                                          (const uint4*)W1_raw, NFEAT * NHID / 8, flag);
  }

  prep_all<<<NN + CONVB, 256, 0, stream>>>(adj, ell_cnt, ell_col,
                                           x_raw, W1_raw, Wa_raw, b1_raw, avec_raw, W3_raw, b3_raw,
                                           xc, W1t, Wat, b1f, avecf, W3f, b3f,
                                           f12a, flag, mode);
  gemm_bt<<<dim3(NN / TM, NHID / TN), 256, 0, stream>>>(xc, NFEAT, W1t, NFEAT, XW, NHID, NFEAT,
                                                        nullptr, nullptr);
  spmm_h1<<<NN / 4, 256, 0, stream>>>(XW, ell_cnt, ell_col, b1f, out2, h1b);
  gemm_bt<<<dim3(NN / TM, NHID / TN), 256, 0, stream>>>(h1b, NHID, Wat, NHID, Wh, NHID, NHID,
                                                        avecf, f12a);

  if (useWS) {
    attn_fused<<<NN, 256, 0, stream>>>(Wh, ell_cnt, ell_col, f12a, W3f, out1, aout, A3);
    spmm_out2<<<NN * NCLASS / 256, 256, 0, stream>>>(A3, ell_cnt, ell_col, b3f, out2, out0, 1);
  } else {
    attn_sparse<<<NN, 256, 0, stream>>>(Wh, ell_cnt, ell_col, f12a, aout);
    gemm3<<<NN / 16, 256, 0, stream>>>(aout, W3f, A3);
    spmm_out2<<<NN * NCLASS / 256, 256, 0, stream>>>(A3, ell_cnt, ell_col, b3f, out2, out0, 0);
    copy_f32<<<(2 * NN + 255) / 256, 256, 0, stream>>>(f12a, f12stash, 2 * NN);
    attn_dense<<<NN, 256, 0, stream>>>(adj, f12stash, out1);
    sigmoid_from_out2<<<NN * NCLASS / 256, 256, 0, stream>>>(out2, out0);
  }
}